// Round 3
// baseline (536.680 us; speedup 1.0000x reference)
//
#include <hip/hip_runtime.h>
#include <math.h>

#define NPTS 8192
#define DCH  256
#define BB   32
#define TOTPT (BB * NPTS)            // 262144 points

// workspace layout (floats)
#define T_OFF     0                          // 32*6*8192 = 1572864
#define X1_OFF    (T_OFF + BB * 6 * NPTS)    // 524288
#define COS_OFF   (X1_OFF + BB * 2 * NPTS)   // 262144
#define SIN_OFF   (COS_OFF + TOTPT)          // 262144
#define X5_OFF    (SIN_OFF + TOTPT)          // 524288
#define STATS_OFF (X5_OFF + BB * 2 * NPTS)   // 128 floats: [0..63] BN1 16x4, [64..127] BN2 16x4

// ---------------------------------------------------------------------------
// block reduce (4 values) + atomic add to dst[0..3]  (dst = 16-way grouped)
// ---------------------------------------------------------------------------
__device__ __forceinline__ void block_reduce_atomic4(float v0, float v1,
                                                     float v2, float v3,
                                                     float* dst)
{
#pragma unroll
    for (int off = 32; off > 0; off >>= 1) {
        v0 += __shfl_down(v0, off, 64);
        v1 += __shfl_down(v1, off, 64);
        v2 += __shfl_down(v2, off, 64);
        v3 += __shfl_down(v3, off, 64);
    }
    __shared__ float red[4][4];
    const int wave = threadIdx.x >> 6, lane = threadIdx.x & 63;
    if (lane == 0) {
        red[wave][0] = v0; red[wave][1] = v1; red[wave][2] = v2; red[wave][3] = v3;
    }
    __syncthreads();
    if (threadIdx.x == 0) {
        float a0 = 0, a1 = 0, a2 = 0, a3 = 0;
#pragma unroll
        for (int w = 0; w < 4; ++w) {
            a0 += red[w][0]; a1 += red[w][1]; a2 += red[w][2]; a3 += red[w][3];
        }
        atomicAdd(dst + 0, a0); atomicAdd(dst + 1, a1);
        atomicAdd(dst + 2, a2); atomicAdd(dst + 3, a3);
    }
}

// ---------------------------------------------------------------------------
// Kernel A: heavy conv (rot 4ch + trans 2ch over feats), channel-split 4 ways
// ACROSS BLOCKS for latency hiding. Grid = 32 b x 32 ntiles x 4 cgroups = 4096
// blocks. Block = 256 thr = 4 waves; wave owns 16 channels (short serial
// chain, unroll 8 => ~24 loads in flight). Partials combined with atomicAdd
// into zero-initialized T (bias added later in kernB).
// ---------------------------------------------------------------------------
__global__ __launch_bounds__(256) void convA(
    const float* __restrict__ feats,
    const float* __restrict__ rot_w,
    const float* __restrict__ trans_w,
    float* __restrict__ T)
{
    const int blk  = blockIdx.x;
    const int cg   = blk & 3;            // channel group (64 ch)
    const int tile = (blk >> 2) & 31;    // 256-pt tile
    const int b    = blk >> 7;           // batch
    const int n0   = tile << 8;
    const int wave = threadIdx.x >> 6;
    const int lane = threadIdx.x & 63;
    const int p    = n0 + (lane << 2);

    const float* fb = feats + (size_t)b * DCH * NPTS;

    float acc[6][4];
#pragma unroll
    for (int o = 0; o < 6; ++o)
#pragma unroll
        for (int j = 0; j < 4; ++j) acc[o][j] = 0.0f;

    // wave-uniform channel base -> SGPR so weight loads become s_load
    const int c0 = __builtin_amdgcn_readfirstlane((cg << 6) + (wave << 4));

    const float lmask = (p > 0) ? 1.0f : 0.0f;
    const int   lidx  = (p > 0) ? (p - 1) : 0;
    const float rmask = (p + 4 < NPTS) ? 1.0f : 0.0f;
    const int   ridx  = (p + 4 < NPTS) ? (p + 4) : 0;

    const float* fr = fb + (size_t)c0 * NPTS;

#pragma unroll 8
    for (int cc = 0; cc < 16; ++cc) {
        const int c = c0 + cc;
        const float4 v = *(const float4*)(fr + p);
        const float fl = fr[lidx] * lmask;
        const float fd = fr[ridx] * rmask;
        const float f[6] = { fl, v.x, v.y, v.z, v.w, fd };
#pragma unroll
        for (int o = 0; o < 6; ++o) {
            const float* wp = (o < 4) ? (rot_w + ((size_t)o * DCH + c) * 3)
                                      : (trans_w + ((size_t)(o - 4) * DCH + c) * 3);
            const float w0 = wp[0], w1 = wp[1], w2 = wp[2];
#pragma unroll
            for (int j = 0; j < 4; ++j)
                acc[o][j] += w0 * f[j] + w1 * f[j + 1] + w2 * f[j + 2];
        }
        fr += NPTS;
    }

    // cross-wave reduce: waves 1..3 dump to LDS, wave 0 sums + atomicAdd to T
    __shared__ float red[3][64][25];   // +1 pad
    if (wave >= 1) {
#pragma unroll
        for (int o = 0; o < 6; ++o)
#pragma unroll
            for (int j = 0; j < 4; ++j)
                red[wave - 1][lane][o * 4 + j] = acc[o][j];
    }
    __syncthreads();
    if (wave == 0) {
#pragma unroll
        for (int q = 0; q < 3; ++q)
#pragma unroll
            for (int o = 0; o < 6; ++o)
#pragma unroll
                for (int j = 0; j < 4; ++j)
                    acc[o][j] += red[q][lane][o * 4 + j];
#pragma unroll
        for (int o = 0; o < 6; ++o) {
            float* dst = T + ((size_t)b * 6 + o) * NPTS + p;
#pragma unroll
            for (int j = 0; j < 4; ++j)
                atomicAdd(dst + j, acc[o][j]);
        }
    }
}

// ---------------------------------------------------------------------------
// Kernel B: read T (+bias), offset expansion + pos-conv (20ch, k=3) +
// BN1 stats + cos/sin(main_rad). 1 thread per point.
// ---------------------------------------------------------------------------
__global__ __launch_bounds__(256) void kernB(
    const float* __restrict__ pts, const float* __restrict__ T,
    const float* __restrict__ rot_b, const float* __restrict__ trans_b,
    const float* __restrict__ pos_w, const float* __restrict__ pos_b,
    float* __restrict__ x1, float* __restrict__ cosA, float* __restrict__ sinA,
    float* __restrict__ stats)
{
    const int g = blockIdx.x * 256 + threadIdx.x;   // 0..262143
    const int b = g >> 13;
    const int n = g & (NPTS - 1);

    float rb[6];
#pragma unroll
    for (int o = 0; o < 4; ++o) rb[o] = rot_b[o];
    rb[4] = trans_b[0]; rb[5] = trans_b[1];

    float xs0 = pos_b[0], xs1 = pos_b[1];
    float mz = -INFINITY;

#pragma unroll
    for (int m3 = 0; m3 < 3; ++m3) {
        const int m   = n + m3 - 1;
        const float msk = (m >= 0 && m < NPTS) ? 1.0f : 0.0f;
        const int mc  = (m < 0) ? 0 : ((m >= NPTS) ? NPTS - 1 : m);

        float t[6];
#pragma unroll
        for (int o = 0; o < 6; ++o)
            t[o] = T[((size_t)b * 6 + o) * NPTS + mc] + rb[o];

        const float pa = pts[((size_t)b * 2 + 0) * NPTS + mc];
        const float pb = pts[((size_t)b * 2 + 1) * NPTS + mc];

        const float o0 = t[0] - 1.0f, o1 = t[1];
        const float o2 = t[2],        o3 = t[3] - 1.0f;
        const float tr0 = t[4],       tr1 = t[5];

        float p0 = pos_w[0 * 60 + 0 * 3 + m3] * pa + pos_w[0 * 60 + 1 * 3 + m3] * pb;
        float p1 = pos_w[1 * 60 + 0 * 3 + m3] * pa + pos_w[1 * 60 + 1 * 3 + m3] * pb;
#pragma unroll
        for (int k = 0; k < 9; ++k) {
            const float R0 = (float)(k / 3 - 1);
            const float R1 = (float)(k % 3 - 1);
            const float cx = o0 * R0 + o1 * R1 + tr0;
            const float cy = o2 * R0 + o3 * R1 + tr1;
            p0 += pos_w[0 * 60 + (2 + 2 * k) * 3 + m3] * cx
                + pos_w[0 * 60 + (3 + 2 * k) * 3 + m3] * cy;
            p1 += pos_w[1 * 60 + (2 + 2 * k) * 3 + m3] * cx
                + pos_w[1 * 60 + (3 + 2 * k) * 3 + m3] * cy;
            if (m3 == 1) {   // center tap: max-arctan via monotone max-z
                const float z = (cy + 1e-6f) / (cx + 1e-6f);
                mz = fmaxf(mz, z);
            }
        }
        xs0 += msk * p0;
        xs1 += msk * p1;
    }

    const float mr = atanf(mz);
    float sv, cv;
    sincosf(mr, &sv, &cv);

    x1[((size_t)b * 2 + 0) * NPTS + n] = xs0;
    x1[((size_t)b * 2 + 1) * NPTS + n] = xs1;
    cosA[g] = cv;
    sinA[g] = sv;

    block_reduce_atomic4(xs0, xs1, xs0 * xs0, xs1 * xs1,
                         stats + ((blockIdx.x & 15) << 2));
}

// ---------------------------------------------------------------------------
// Kernel D: BN1 apply + leaky + rotate + ori-conv + BN2 stats. 1 thr/point.
// ---------------------------------------------------------------------------
__global__ __launch_bounds__(256) void kernD(
    const float* __restrict__ x1,
    const float* __restrict__ cosA, const float* __restrict__ sinA,
    const float* __restrict__ pos_g, const float* __restrict__ pos_beta,
    const float* __restrict__ ori_w, const float* __restrict__ ori_b,
    float* __restrict__ stats, float* __restrict__ x5)
{
    const int gg = blockIdx.x * 256 + threadIdx.x;
    const int b = gg >> 13;
    const int n = gg & (NPTS - 1);

    float s0 = 0, s1 = 0, s2 = 0, s3 = 0;
#pragma unroll
    for (int q = 0; q < 16; ++q) {
        s0 += stats[q * 4 + 0]; s1 += stats[q * 4 + 1];
        s2 += stats[q * 4 + 2]; s3 += stats[q * 4 + 3];
    }
    const float cntInv = 1.0f / (float)TOTPT;
    const float m0 = s0 * cntInv, m1 = s1 * cntInv;
    const float var0 = s2 * cntInv - m0 * m0;
    const float var1 = s3 * cntInv - m1 * m1;
    const float i0 = rsqrtf(var0 + 1e-5f), i1 = rsqrtf(var1 + 1e-5f);
    const float g0 = pos_g[0], g1 = pos_g[1];
    const float be0 = pos_beta[0], be1 = pos_beta[1];

    float x4a[3], x4b[3];
#pragma unroll
    for (int m3 = 0; m3 < 3; ++m3) {
        const int m   = n + m3 - 1;
        const float msk = (m >= 0 && m < NPTS) ? 1.0f : 0.0f;
        const int mc  = (m < 0) ? 0 : ((m >= NPTS) ? NPTS - 1 : m);
        float y0 = x1[((size_t)b * 2 + 0) * NPTS + mc];
        float y1 = x1[((size_t)b * 2 + 1) * NPTS + mc];
        y0 = g0 * (y0 - m0) * i0 + be0;
        y1 = g1 * (y1 - m1) * i1 + be1;
        y0 = (y0 >= 0.0f) ? y0 : 0.2f * y0;
        y1 = (y1 >= 0.0f) ? y1 : 0.2f * y1;
        const float cv = cosA[(b << 13) + mc];
        const float sv = sinA[(b << 13) + mc];
        x4a[m3] = (y0 * cv - y1 * sv) * msk;
        x4b[m3] = (y0 * sv + y1 * cv) * msk;
    }

    float z0 = ori_b[0], z1 = ori_b[1];
#pragma unroll
    for (int k = 0; k < 3; ++k) {
        z0 += ori_w[0 * 6 + 0 * 3 + k] * x4a[k] + ori_w[0 * 6 + 1 * 3 + k] * x4b[k];
        z1 += ori_w[1 * 6 + 0 * 3 + k] * x4a[k] + ori_w[1 * 6 + 1 * 3 + k] * x4b[k];
    }
    x5[((size_t)b * 2 + 0) * NPTS + n] = z0;
    x5[((size_t)b * 2 + 1) * NPTS + n] = z1;

    block_reduce_atomic4(z0, z1, z0 * z0, z1 * z1,
                         stats + 64 + ((blockIdx.x & 15) << 2));
}

// ---------------------------------------------------------------------------
// Kernel E: BN2 apply -> out
// ---------------------------------------------------------------------------
__global__ __launch_bounds__(256) void kernE(
    const float* __restrict__ x5, const float* __restrict__ stats,
    const float* __restrict__ ori_g, const float* __restrict__ ori_beta,
    float* __restrict__ out)
{
    const int gg = blockIdx.x * 256 + threadIdx.x;  // 0..524287
    const int o = (gg >> 13) & 1;
    float sm = 0, sq = 0;
#pragma unroll
    for (int q = 0; q < 16; ++q) {
        sm += stats[64 + q * 4 + o];
        sq += stats[64 + q * 4 + 2 + o];
    }
    const float cntInv = 1.0f / (float)TOTPT;
    const float m  = sm * cntInv;
    const float vv = sq * cntInv - m * m;
    const float inv = rsqrtf(vv + 1e-5f);
    out[gg] = ori_g[o] * (x5[gg] - m) * inv + ori_beta[o];
}

// ---------------------------------------------------------------------------
extern "C" void kernel_launch(void* const* d_in, const int* in_sizes, int n_in,
                              void* d_out, int out_size, void* d_ws, size_t ws_size,
                              hipStream_t stream)
{
    const float* pts      = (const float*)d_in[0];
    const float* feats    = (const float*)d_in[1];
    const float* rot_w    = (const float*)d_in[2];
    const float* rot_b    = (const float*)d_in[3];
    const float* trans_w  = (const float*)d_in[4];
    const float* trans_b  = (const float*)d_in[5];
    const float* pos_w    = (const float*)d_in[6];
    const float* pos_b    = (const float*)d_in[7];
    const float* pos_g    = (const float*)d_in[8];
    const float* pos_beta = (const float*)d_in[9];
    const float* ori_w    = (const float*)d_in[10];
    const float* ori_b    = (const float*)d_in[11];
    const float* ori_g    = (const float*)d_in[12];
    const float* ori_beta = (const float*)d_in[13];

    float* ws    = (float*)d_ws;
    float* T     = ws + T_OFF;
    float* x1    = ws + X1_OFF;
    float* cosA  = ws + COS_OFF;
    float* sinA  = ws + SIN_OFF;
    float* x5    = ws + X5_OFF;
    float* stats = ws + STATS_OFF;

    hipMemsetAsync(T, 0, (size_t)BB * 6 * NPTS * sizeof(float), stream);
    hipMemsetAsync(stats, 0, 128 * sizeof(float), stream);

    convA<<<4096, 256, 0, stream>>>(feats, rot_w, trans_w, T);
    kernB<<<1024, 256, 0, stream>>>(pts, T, rot_b, trans_b, pos_w, pos_b,
                                    x1, cosA, sinA, stats);
    kernD<<<1024, 256, 0, stream>>>(x1, cosA, sinA, pos_g, pos_beta,
                                    ori_w, ori_b, stats, x5);
    kernE<<<2048, 256, 0, stream>>>(x5, stats, ori_g, ori_beta, (float*)d_out);
}

// Round 4
// 499.139 us; speedup vs baseline: 1.0752x; 1.0752x over previous
//
#include <hip/hip_runtime.h>
#include <math.h>

#define NPTS 8192
#define DCH  256
#define BB   32
#define TOTPT (BB * NPTS)            // 262144 points

// workspace layout (floats)
#define X1_OFF    0                          // 32*2*8192 = 524288
#define COS_OFF   (X1_OFF + BB * 2 * NPTS)   // 262144
#define SIN_OFF   (COS_OFF + TOTPT)          // 262144
#define X5_OFF    (SIN_OFF + TOTPT)          // 524288
#define STATS_OFF (X5_OFF + BB * 2 * NPTS)   // 128 floats: [0..63] BN1 16x4, [64..127] BN2 16x4

// ---------------------------------------------------------------------------
// block reduce (4 values) + atomic add to dst[0..3]  (dst = 16-way grouped)
// ---------------------------------------------------------------------------
__device__ __forceinline__ void block_reduce_atomic4(float v0, float v1,
                                                     float v2, float v3,
                                                     float* dst)
{
#pragma unroll
    for (int off = 32; off > 0; off >>= 1) {
        v0 += __shfl_down(v0, off, 64);
        v1 += __shfl_down(v1, off, 64);
        v2 += __shfl_down(v2, off, 64);
        v3 += __shfl_down(v3, off, 64);
    }
    __shared__ float red[4][4];
    const int wave = threadIdx.x >> 6, lane = threadIdx.x & 63;
    if (lane == 0) {
        red[wave][0] = v0; red[wave][1] = v1; red[wave][2] = v2; red[wave][3] = v3;
    }
    __syncthreads();
    if (threadIdx.x == 0) {
        float a0 = 0, a1 = 0, a2 = 0, a3 = 0;
#pragma unroll
        for (int w = 0; w < 4; ++w) {
            a0 += red[w][0]; a1 += red[w][1]; a2 += red[w][2]; a3 += red[w][3];
        }
        atomicAdd(dst + 0, a0); atomicAdd(dst + 1, a1);
        atomicAdd(dst + 2, a2); atomicAdd(dst + 3, a3);
    }
}

// ---------------------------------------------------------------------------
// Fused kernel AB: heavy conv (rot 4ch + trans 2ch over feats) staged in LDS
// (incl. 1-pt halo each side, recomputed in-block) + offset expansion +
// pos-conv (20ch, k=3) + BN1 stats + cos/sin(main_rad).
// Block: 256 thr = 4 waves; each wave owns 64 channels; tile = 256 points.
// NOTE (R3 post-mortem): this kernel runs concurrently with ~1.3 GB of
// harness reset traffic and gets leftover HBM BW (~1.4 TB/s). Duration is
// bytes-determined; occupancy/latency tuning was measured neutral. Keep
// total bytes minimal (no T round-trip, no global atomics on T).
// ---------------------------------------------------------------------------
__global__ __launch_bounds__(256) void kernAB(
    const float* __restrict__ pts, const float* __restrict__ feats,
    const float* __restrict__ rot_w, const float* __restrict__ rot_b,
    const float* __restrict__ trans_w, const float* __restrict__ trans_b,
    const float* __restrict__ pos_w, const float* __restrict__ pos_b,
    float* __restrict__ x1, float* __restrict__ cosA, float* __restrict__ sinA,
    float* __restrict__ stats)
{
    const int blk  = blockIdx.x;
    const int b    = blk >> 5;
    const int n0   = (blk & 31) << 8;
    const int tid  = threadIdx.x;
    const int wave = tid >> 6;
    const int lane = tid & 63;
    const int p    = n0 + (lane << 2);

    const float* fb = feats + (size_t)b * DCH * NPTS;

    __shared__ float red[3][64][25];   // cross-wave acc reduction (+1 pad)
    __shared__ float hw4[4][12];       // per-wave halo partial sums
    __shared__ float Tsh[6][260];      // conv result tile: idx 0..257 = n0-1..n0+256

    // ---------------- phase 1: main conv tile ----------------
    float acc[6][4];
#pragma unroll
    for (int o = 0; o < 6; ++o)
#pragma unroll
        for (int j = 0; j < 4; ++j) acc[o][j] = 0.0f;

    const int c0 = __builtin_amdgcn_readfirstlane(wave << 6);

    const float lmask = (p > 0) ? 1.0f : 0.0f;
    const int   lidx  = (p > 0) ? (p - 1) : 0;
    const float rmask = (p + 4 < NPTS) ? 1.0f : 0.0f;
    const int   ridx  = (p + 4 < NPTS) ? (p + 4) : 0;

    const float* fr = fb + (size_t)c0 * NPTS;

#pragma unroll 4
    for (int cc = 0; cc < 64; ++cc) {
        const int c = c0 + cc;
        const float4 v = *(const float4*)(fr + p);
        const float fl = fr[lidx] * lmask;
        const float fd = fr[ridx] * rmask;
        const float f[6] = { fl, v.x, v.y, v.z, v.w, fd };
#pragma unroll
        for (int o = 0; o < 6; ++o) {
            const float* wp = (o < 4) ? (rot_w + ((size_t)o * DCH + c) * 3)
                                      : (trans_w + ((size_t)(o - 4) * DCH + c) * 3);
            const float w0 = wp[0], w1 = wp[1], w2 = wp[2];
#pragma unroll
            for (int j = 0; j < 4; ++j)
                acc[o][j] += w0 * f[j] + w1 * f[j + 1] + w2 * f[j + 2];
        }
        fr += NPTS;
    }

    // ---------------- phase 1b: halo conv points (n0-1 and n0+256) ----------
    // per-thread channel = tid; partials reduced across the block.
    float hh[12];
    {
        const float* fc = fb + (size_t)tid * NPTS;
        const int iA = (n0 >= 2) ? (n0 - 2) : 0;     // masked downstream if n0==0
        const int iB = (n0 >= 1) ? (n0 - 1) : 0;
        const float a0 = fc[iA], a1 = fc[iB], a2 = fc[n0];
        const int jB = (n0 + 256 <= NPTS - 1) ? (n0 + 256) : (NPTS - 1);
        const int jC = (n0 + 257 <= NPTS - 1) ? (n0 + 257) : (NPTS - 1);
        const float b0 = fc[n0 + 255], b1 = fc[jB], b2 = fc[jC];
#pragma unroll
        for (int o = 0; o < 6; ++o) {
            const float* wp = (o < 4) ? (rot_w + ((size_t)o * DCH + tid) * 3)
                                      : (trans_w + ((size_t)(o - 4) * DCH + tid) * 3);
            const float w0 = wp[0], w1 = wp[1], w2 = wp[2];
            hh[o]     = w0 * a0 + w1 * a1 + w2 * a2;   // left halo
            hh[6 + o] = w0 * b0 + w1 * b1 + w2 * b2;   // right halo
        }
    }
#pragma unroll
    for (int off = 32; off > 0; off >>= 1)
#pragma unroll
        for (int j = 0; j < 12; ++j)
            hh[j] += __shfl_down(hh[j], off, 64);

    if (wave >= 1) {
#pragma unroll
        for (int o = 0; o < 6; ++o)
#pragma unroll
            for (int j = 0; j < 4; ++j)
                red[wave - 1][lane][o * 4 + j] = acc[o][j];
    }
    if (lane == 0) {
#pragma unroll
        for (int j = 0; j < 12; ++j) hw4[wave][j] = hh[j];
    }
    __syncthreads();

    if (wave == 0) {
#pragma unroll
        for (int q = 0; q < 3; ++q)
#pragma unroll
            for (int o = 0; o < 6; ++o)
#pragma unroll
                for (int j = 0; j < 4; ++j)
                    acc[o][j] += red[q][lane][o * 4 + j];
#pragma unroll
        for (int o = 0; o < 6; ++o) {
            const float bias = (o < 4) ? rot_b[o] : trans_b[o - 4];
#pragma unroll
            for (int j = 0; j < 4; ++j)
                Tsh[o][1 + (lane << 2) + j] = acc[o][j] + bias;
        }
    }
    if (tid < 12) {
        const int o = tid % 6, side = tid / 6;
        float v = hw4[0][tid] + hw4[1][tid] + hw4[2][tid] + hw4[3][tid];
        v += (o < 4) ? rot_b[o] : trans_b[o - 4];
        Tsh[o][side ? 257 : 0] = v;
    }
    __syncthreads();

    // ---------------- phase 2: offsets + pos-conv + rad ----------------
    const int n = n0 + tid;
    float tm[6][3];
#pragma unroll
    for (int o = 0; o < 6; ++o)
#pragma unroll
        for (int k = 0; k < 3; ++k)
            tm[o][k] = Tsh[o][tid + k];

    float xs0 = pos_b[0], xs1 = pos_b[1];
    float mz = -INFINITY;

#pragma unroll
    for (int m3 = 0; m3 < 3; ++m3) {
        const int m   = n + m3 - 1;
        const float msk = (m >= 0 && m < NPTS) ? 1.0f : 0.0f;
        const int mc  = (m < 0) ? 0 : ((m >= NPTS) ? NPTS - 1 : m);

        const float pa = pts[((size_t)b * 2 + 0) * NPTS + mc];
        const float pb = pts[((size_t)b * 2 + 1) * NPTS + mc];

        const float o0 = tm[0][m3] - 1.0f, o1 = tm[1][m3];
        const float o2 = tm[2][m3],        o3 = tm[3][m3] - 1.0f;
        const float tr0 = tm[4][m3],       tr1 = tm[5][m3];

        float p0 = pos_w[0 * 60 + 0 * 3 + m3] * pa + pos_w[0 * 60 + 1 * 3 + m3] * pb;
        float p1 = pos_w[1 * 60 + 0 * 3 + m3] * pa + pos_w[1 * 60 + 1 * 3 + m3] * pb;
#pragma unroll
        for (int k = 0; k < 9; ++k) {
            const float R0 = (float)(k / 3 - 1);
            const float R1 = (float)(k % 3 - 1);
            const float cx = o0 * R0 + o1 * R1 + tr0;
            const float cy = o2 * R0 + o3 * R1 + tr1;
            p0 += pos_w[0 * 60 + (2 + 2 * k) * 3 + m3] * cx
                + pos_w[0 * 60 + (3 + 2 * k) * 3 + m3] * cy;
            p1 += pos_w[1 * 60 + (2 + 2 * k) * 3 + m3] * cx
                + pos_w[1 * 60 + (3 + 2 * k) * 3 + m3] * cy;
            if (m3 == 1) {   // center tap: feed max-arctan (monotone => max z)
                const float z = (cy + 1e-6f) / (cx + 1e-6f);
                mz = fmaxf(mz, z);
            }
        }
        xs0 += msk * p0;
        xs1 += msk * p1;
    }

    const float mr = atanf(mz);
    float sv, cv;
    sincosf(mr, &sv, &cv);

    const int g = (b << 13) + n;
    x1[((size_t)b * 2 + 0) * NPTS + n] = xs0;
    x1[((size_t)b * 2 + 1) * NPTS + n] = xs1;
    cosA[g] = cv;
    sinA[g] = sv;

    block_reduce_atomic4(xs0, xs1, xs0 * xs0, xs1 * xs1,
                         stats + ((blk & 15) << 2));
}

// ---------------------------------------------------------------------------
// Kernel D: BN1 apply + leaky + rotate + ori-conv + BN2 stats. 1 thr/point.
// ---------------------------------------------------------------------------
__global__ __launch_bounds__(256) void kernD(
    const float* __restrict__ x1,
    const float* __restrict__ cosA, const float* __restrict__ sinA,
    const float* __restrict__ pos_g, const float* __restrict__ pos_beta,
    const float* __restrict__ ori_w, const float* __restrict__ ori_b,
    float* __restrict__ stats, float* __restrict__ x5)
{
    const int gg = blockIdx.x * 256 + threadIdx.x;
    const int b = gg >> 13;
    const int n = gg & (NPTS - 1);

    float s0 = 0, s1 = 0, s2 = 0, s3 = 0;
#pragma unroll
    for (int q = 0; q < 16; ++q) {
        s0 += stats[q * 4 + 0]; s1 += stats[q * 4 + 1];
        s2 += stats[q * 4 + 2]; s3 += stats[q * 4 + 3];
    }
    const float cntInv = 1.0f / (float)TOTPT;
    const float m0 = s0 * cntInv, m1 = s1 * cntInv;
    const float var0 = s2 * cntInv - m0 * m0;
    const float var1 = s3 * cntInv - m1 * m1;
    const float i0 = rsqrtf(var0 + 1e-5f), i1 = rsqrtf(var1 + 1e-5f);
    const float g0 = pos_g[0], g1 = pos_g[1];
    const float be0 = pos_beta[0], be1 = pos_beta[1];

    float x4a[3], x4b[3];
#pragma unroll
    for (int m3 = 0; m3 < 3; ++m3) {
        const int m   = n + m3 - 1;
        const float msk = (m >= 0 && m < NPTS) ? 1.0f : 0.0f;
        const int mc  = (m < 0) ? 0 : ((m >= NPTS) ? NPTS - 1 : m);
        float y0 = x1[((size_t)b * 2 + 0) * NPTS + mc];
        float y1 = x1[((size_t)b * 2 + 1) * NPTS + mc];
        y0 = g0 * (y0 - m0) * i0 + be0;
        y1 = g1 * (y1 - m1) * i1 + be1;
        y0 = (y0 >= 0.0f) ? y0 : 0.2f * y0;
        y1 = (y1 >= 0.0f) ? y1 : 0.2f * y1;
        const float cv = cosA[(b << 13) + mc];
        const float sv = sinA[(b << 13) + mc];
        x4a[m3] = (y0 * cv - y1 * sv) * msk;
        x4b[m3] = (y0 * sv + y1 * cv) * msk;
    }

    float z0 = ori_b[0], z1 = ori_b[1];
#pragma unroll
    for (int k = 0; k < 3; ++k) {
        z0 += ori_w[0 * 6 + 0 * 3 + k] * x4a[k] + ori_w[0 * 6 + 1 * 3 + k] * x4b[k];
        z1 += ori_w[1 * 6 + 0 * 3 + k] * x4a[k] + ori_w[1 * 6 + 1 * 3 + k] * x4b[k];
    }
    x5[((size_t)b * 2 + 0) * NPTS + n] = z0;
    x5[((size_t)b * 2 + 1) * NPTS + n] = z1;

    block_reduce_atomic4(z0, z1, z0 * z0, z1 * z1,
                         stats + 64 + ((blockIdx.x & 15) << 2));
}

// ---------------------------------------------------------------------------
// Kernel E: BN2 apply -> out
// ---------------------------------------------------------------------------
__global__ __launch_bounds__(256) void kernE(
    const float* __restrict__ x5, const float* __restrict__ stats,
    const float* __restrict__ ori_g, const float* __restrict__ ori_beta,
    float* __restrict__ out)
{
    const int gg = blockIdx.x * 256 + threadIdx.x;  // 0..524287
    const int o = (gg >> 13) & 1;
    float sm = 0, sq = 0;
#pragma unroll
    for (int q = 0; q < 16; ++q) {
        sm += stats[64 + q * 4 + o];
        sq += stats[64 + q * 4 + 2 + o];
    }
    const float cntInv = 1.0f / (float)TOTPT;
    const float m  = sm * cntInv;
    const float vv = sq * cntInv - m * m;
    const float inv = rsqrtf(vv + 1e-5f);
    out[gg] = ori_g[o] * (x5[gg] - m) * inv + ori_beta[o];
}

// ---------------------------------------------------------------------------
extern "C" void kernel_launch(void* const* d_in, const int* in_sizes, int n_in,
                              void* d_out, int out_size, void* d_ws, size_t ws_size,
                              hipStream_t stream)
{
    const float* pts      = (const float*)d_in[0];
    const float* feats    = (const float*)d_in[1];
    const float* rot_w    = (const float*)d_in[2];
    const float* rot_b    = (const float*)d_in[3];
    const float* trans_w  = (const float*)d_in[4];
    const float* trans_b  = (const float*)d_in[5];
    const float* pos_w    = (const float*)d_in[6];
    const float* pos_b    = (const float*)d_in[7];
    const float* pos_g    = (const float*)d_in[8];
    const float* pos_beta = (const float*)d_in[9];
    const float* ori_w    = (const float*)d_in[10];
    const float* ori_b    = (const float*)d_in[11];
    const float* ori_g    = (const float*)d_in[12];
    const float* ori_beta = (const float*)d_in[13];

    float* ws    = (float*)d_ws;
    float* x1    = ws + X1_OFF;
    float* cosA  = ws + COS_OFF;
    float* sinA  = ws + SIN_OFF;
    float* x5    = ws + X5_OFF;
    float* stats = ws + STATS_OFF;

    hipMemsetAsync(stats, 0, 128 * sizeof(float), stream);

    kernAB<<<1024, 256, 0, stream>>>(pts, feats, rot_w, rot_b, trans_w, trans_b,
                                     pos_w, pos_b, x1, cosA, sinA, stats);
    kernD<<<1024, 256, 0, stream>>>(x1, cosA, sinA, pos_g, pos_beta,
                                    ori_w, ori_b, stats, x5);
    kernE<<<2048, 256, 0, stream>>>(x5, stats, ori_g, ori_beta, (float*)d_out);
}